// Round 1
// baseline (569.527 us; speedup 1.0000x reference)
//
#include <hip/hip_runtime.h>

#define HIDDEN 64
#define HALFD  32
#define VOCAB  64
#define BATCH  256
#define SEQLEN 2048

// ---------------------------------------------------------------------------
// Kernel 1: per-token vocab tables.
// h = LN(e + FF(e)); hs = h@Ws.T+bs; he = h@We.T+be; store normalized keys
// and raw values for both branches into ws:
//   ws[0    ..2047]  ks_voc [64][32]  (normalized hs)
//   ws[2048 ..4095]  ke_voc [64][32]  (normalized he)
//   ws[4096 ..6143]  vs_voc [64][32]  (raw hs)
//   ws[6144 ..8191]  ve_voc [64][32]  (raw he)
// ---------------------------------------------------------------------------
__global__ __launch_bounds__(64) void vocab_kernel(
    const float* __restrict__ embed, const float* __restrict__ W1, const float* __restrict__ b1,
    const float* __restrict__ W2, const float* __restrict__ b2,
    const float* __restrict__ ln_g, const float* __restrict__ ln_b,
    const float* __restrict__ Ws, const float* __restrict__ bs,
    const float* __restrict__ We, const float* __restrict__ be,
    float* __restrict__ ws)
{
    const int v = blockIdx.x;      // token id
    const int tid = threadIdx.x;   // 0..63  (one wave)

    __shared__ float e_s[64];
    __shared__ float a1_s[128];
    __shared__ float h_s[64];

    e_s[tid] = embed[v * 64 + tid];
    __syncthreads();

    // FF layer 1 (+ReLU): thread computes rows tid and tid+64 of W1
    float acc0 = b1[tid], acc1 = b1[tid + 64];
    #pragma unroll 8
    for (int m = 0; m < 64; ++m) {
        float ev = e_s[m];
        acc0 = fmaf(ev, W1[tid * 64 + m], acc0);
        acc1 = fmaf(ev, W1[(tid + 64) * 64 + m], acc1);
    }
    a1_s[tid]      = fmaxf(acc0, 0.0f);
    a1_s[tid + 64] = fmaxf(acc1, 0.0f);
    __syncthreads();

    // FF layer 2
    float ff = b2[tid];
    #pragma unroll 8
    for (int m = 0; m < 128; ++m) ff = fmaf(a1_s[m], W2[tid * 128 + m], ff);
    float x = e_s[tid] + ff;

    // LayerNorm across the 64-lane wave
    float s = x, s2 = x * x;
    #pragma unroll
    for (int off = 32; off >= 1; off >>= 1) {
        s  += __shfl_xor(s,  off, 64);
        s2 += __shfl_xor(s2, off, 64);
    }
    float mu  = s * (1.0f / 64.0f);
    float var = s2 * (1.0f / 64.0f) - mu * mu;
    float hval = (x - mu) * rsqrtf(var + 1e-5f) * ln_g[tid] + ln_b[tid];
    h_s[tid] = hval;
    __syncthreads();

    // hs (lanes 0..31) / he (lanes 32..63) projections
    const int j = tid & 31;
    const bool is_s = tid < 32;
    const float* W = is_s ? Ws : We;
    float acc = is_s ? bs[j] : be[j];
    #pragma unroll 8
    for (int m = 0; m < 64; ++m) acc = fmaf(h_s[m], W[j * 64 + m], acc);

    // half-wave L2 norm (xor masks <= 16 stay within each 32-lane half)
    float n2 = acc * acc;
    #pragma unroll
    for (int off = 16; off >= 1; off >>= 1) n2 += __shfl_xor(n2, off, 64);
    float norm = sqrtf(n2);
    float kn = acc / fmaxf(norm, 1e-12f);

    const int base = v * 32 + j;
    if (is_s) { ws[base]        = kn; ws[4096 + base] = acc; }
    else      { ws[2048 + base] = kn; ws[6144 + base] = acc; }
}

// ---------------------------------------------------------------------------
// Kernel 2: delta-rule scan + readout head.
// One block per batch. Wave 0 owns M_s, wave 1 owns M_e.
// Lane layout within a wave: row = lane&31, half = lane>>5; each lane holds
// M[row][half*16 .. half*16+15] in registers.
// ---------------------------------------------------------------------------
__global__ __launch_bounds__(128) void scan_kernel(
    const int* __restrict__ seq, const float* __restrict__ ws,
    const float* __restrict__ Wrp, const float* __restrict__ brp,
    const float* __restrict__ Wo, const float* __restrict__ bo,
    float* __restrict__ out)
{
    const int b    = blockIdx.x;
    const int tid  = threadIdx.x;   // 0..127
    const int w    = tid >> 6;      // 0: M_s, 1: M_e
    const int lane = tid & 63;
    const int row  = lane & 31;
    const int half = lane >> 5;
    const int col0 = half << 4;

    __shared__ __align__(16) float kvoc[4096];   // [w][tok][col]
    __shared__ __align__(16) float vvoc[4096];
    __shared__ int   tok_s[SEQLEN];
    __shared__ float r_s[64];
    __shared__ float t1_s[64];

    for (int i = tid; i < 4096; i += 128) { kvoc[i] = ws[i]; vvoc[i] = ws[4096 + i]; }
    const int* sq = seq + b * SEQLEN;
    for (int i = tid; i < SEQLEN; i += 128) tok_s[i] = sq[i];
    __syncthreads();

    const float* kb = kvoc + w * 2048;
    const float* vb = vvoc + w * 2048;

    float M[16];
    #pragma unroll
    for (int j = 0; j < 16; ++j) M[j] = 0.0f;

    const float invL = 1.0f / (float)SEQLEN;
    const bool  is_e = (w == 1);

    // software pipeline: pk*/pkr/pvr hold data for step t at top of iter t
    int tokA = tok_s[0];
    float4 pk0 = *(const float4*)(kb + tokA * 32 + col0);
    float4 pk1 = *(const float4*)(kb + tokA * 32 + col0 + 4);
    float4 pk2 = *(const float4*)(kb + tokA * 32 + col0 + 8);
    float4 pk3 = *(const float4*)(kb + tokA * 32 + col0 + 12);
    float  pkr = kb[tokA * 32 + row];
    float  pvr = vb[tokA * 32 + row];
    int tokB = tok_s[1];

    for (int t = 0; t < SEQLEN - 1; ++t) {
        // current step data
        float k0 = pk0.x, k1 = pk0.y, k2 = pk0.z, k3 = pk0.w;
        float k4 = pk1.x, k5 = pk1.y, k6 = pk1.z, k7 = pk1.w;
        float k8 = pk2.x, k9 = pk2.y, k10 = pk2.z, k11 = pk2.w;
        float k12 = pk3.x, k13 = pk3.y, k14 = pk3.z, k15 = pk3.w;
        float cv = pvr;

        // prefetch step t+1 (at t==SEQLEN-2 this loads the query key)
        {
            const int ta = tokB;
            pk0 = *(const float4*)(kb + ta * 32 + col0);
            pk1 = *(const float4*)(kb + ta * 32 + col0 + 4);
            pk2 = *(const float4*)(kb + ta * 32 + col0 + 8);
            pk3 = *(const float4*)(kb + ta * 32 + col0 + 12);
            pkr = kb[ta * 32 + row];
            pvr = vb[ta * 32 + row];
            tokB = tok_s[(t + 2) & (SEQLEN - 1)];
        }

        // vps[row] = sum_j M[row][j] * k[j]  (two half-rows via shfl_xor 32)
        float a0 = fmaf(M[0], k0, fmaf(M[1], k1, fmaf(M[2], k2, M[3] * k3)));
        float a1 = fmaf(M[4], k4, fmaf(M[5], k5, fmaf(M[6], k6, M[7] * k7)));
        float a2 = fmaf(M[8], k8, fmaf(M[9], k9, fmaf(M[10], k10, M[11] * k11)));
        float a3 = fmaf(M[12], k12, fmaf(M[13], k13, fmaf(M[14], k14, M[15] * k15)));
        float partial = (a0 + a1) + (a2 + a3);
        float tot = partial + __shfl_xor(partial, 32, 64);

        float fac = is_e ? (float)(t + 1) * invL : 1.0f;
        float delta = (cv - tot) * fac;

        M[0]  = fmaf(delta, k0,  M[0]);  M[1]  = fmaf(delta, k1,  M[1]);
        M[2]  = fmaf(delta, k2,  M[2]);  M[3]  = fmaf(delta, k3,  M[3]);
        M[4]  = fmaf(delta, k4,  M[4]);  M[5]  = fmaf(delta, k5,  M[5]);
        M[6]  = fmaf(delta, k6,  M[6]);  M[7]  = fmaf(delta, k7,  M[7]);
        M[8]  = fmaf(delta, k8,  M[8]);  M[9]  = fmaf(delta, k9,  M[9]);
        M[10] = fmaf(delta, k10, M[10]); M[11] = fmaf(delta, k11, M[11]);
        M[12] = fmaf(delta, k12, M[12]); M[13] = fmaf(delta, k13, M[13]);
        M[14] = fmaf(delta, k14, M[14]); M[15] = fmaf(delta, k15, M[15]);
    }

    // epilogue: pk* now hold the normalized key of token[SEQLEN-1] (the query)
    {
        float q0 = pk0.x, q1 = pk0.y, q2 = pk0.z, q3 = pk0.w;
        float q4 = pk1.x, q5 = pk1.y, q6 = pk1.z, q7 = pk1.w;
        float q8 = pk2.x, q9 = pk2.y, q10 = pk2.z, q11 = pk2.w;
        float q12 = pk3.x, q13 = pk3.y, q14 = pk3.z, q15 = pk3.w;
        float a0 = fmaf(M[0], q0, fmaf(M[1], q1, fmaf(M[2], q2, M[3] * q3)));
        float a1 = fmaf(M[4], q4, fmaf(M[5], q5, fmaf(M[6], q6, M[7] * q7)));
        float a2 = fmaf(M[8], q8, fmaf(M[9], q9, fmaf(M[10], q10, M[11] * q11)));
        float a3 = fmaf(M[12], q12, fmaf(M[13], q13, fmaf(M[14], q14, M[15] * q15)));
        float partial = (a0 + a1) + (a2 + a3);
        float tot = partial + __shfl_xor(partial, 32, 64);
        if (half == 0) r_s[w * 32 + row] = tot;   // r = [rs | re]
    }
    __syncthreads();

    // out = (r @ Wrp.T + brp) @ Wo.T + bo
    if (tid < 64) {
        float acc = brp[tid];
        #pragma unroll 8
        for (int m = 0; m < 64; ++m) acc = fmaf(Wrp[tid * 64 + m], r_s[m], acc);
        t1_s[tid] = acc;
    }
    __syncthreads();
    if (tid < 64) {
        float acc = bo[tid];
        #pragma unroll 8
        for (int m = 0; m < 64; ++m) acc = fmaf(Wo[tid * 64 + m], t1_s[m], acc);
        out[b * 64 + tid] = acc;
    }
}

extern "C" void kernel_launch(void* const* d_in, const int* in_sizes, int n_in,
                              void* d_out, int out_size, void* d_ws, size_t ws_size,
                              hipStream_t stream)
{
    const int*   seq   = (const int*)  d_in[0];
    const float* embed = (const float*)d_in[1];
    const float* W1    = (const float*)d_in[2];
    const float* b1    = (const float*)d_in[3];
    const float* W2    = (const float*)d_in[4];
    const float* b2    = (const float*)d_in[5];
    const float* ln_g  = (const float*)d_in[6];
    const float* ln_b  = (const float*)d_in[7];
    const float* Ws    = (const float*)d_in[8];
    const float* bs    = (const float*)d_in[9];
    const float* We    = (const float*)d_in[10];
    const float* be    = (const float*)d_in[11];
    const float* Wrp   = (const float*)d_in[12];
    const float* brp   = (const float*)d_in[13];
    const float* Wo    = (const float*)d_in[14];
    const float* bo    = (const float*)d_in[15];
    float* ws  = (float*)d_ws;
    float* out = (float*)d_out;

    hipLaunchKernelGGL(vocab_kernel, dim3(VOCAB), dim3(64), 0, stream,
                       embed, W1, b1, W2, b2, ln_g, ln_b, Ws, bs, We, be, ws);
    hipLaunchKernelGGL(scan_kernel, dim3(BATCH), dim3(128), 0, stream,
                       seq, ws, Wrp, brp, Wo, bo, out);
}

// Round 2
// 420.189 us; speedup vs baseline: 1.3554x; 1.3554x over previous
//
#include <hip/hip_runtime.h>

#define HIDDEN 64
#define HALFD  32
#define VOCAB  64
#define BATCH  256
#define SEQLEN 2048

// ---------------------------------------------------------------------------
// Kernel 1: per-token vocab tables (unchanged from R1).
//   ws[0    ..2047]  ks_voc [64][32]  (normalized hs)
//   ws[2048 ..4095]  ke_voc [64][32]  (normalized he)
//   ws[4096 ..6143]  vs_voc [64][32]  (raw hs)
//   ws[6144 ..8191]  ve_voc [64][32]  (raw he)
// ---------------------------------------------------------------------------
__global__ __launch_bounds__(64) void vocab_kernel(
    const float* __restrict__ embed, const float* __restrict__ W1, const float* __restrict__ b1,
    const float* __restrict__ W2, const float* __restrict__ b2,
    const float* __restrict__ ln_g, const float* __restrict__ ln_b,
    const float* __restrict__ Ws, const float* __restrict__ bs,
    const float* __restrict__ We, const float* __restrict__ be,
    float* __restrict__ ws)
{
    const int v = blockIdx.x;
    const int tid = threadIdx.x;

    __shared__ float e_s[64];
    __shared__ float a1_s[128];
    __shared__ float h_s[64];

    e_s[tid] = embed[v * 64 + tid];
    __syncthreads();

    float acc0 = b1[tid], acc1 = b1[tid + 64];
    #pragma unroll 8
    for (int m = 0; m < 64; ++m) {
        float ev = e_s[m];
        acc0 = fmaf(ev, W1[tid * 64 + m], acc0);
        acc1 = fmaf(ev, W1[(tid + 64) * 64 + m], acc1);
    }
    a1_s[tid]      = fmaxf(acc0, 0.0f);
    a1_s[tid + 64] = fmaxf(acc1, 0.0f);
    __syncthreads();

    float ff = b2[tid];
    #pragma unroll 8
    for (int m = 0; m < 128; ++m) ff = fmaf(a1_s[m], W2[tid * 128 + m], ff);
    float x = e_s[tid] + ff;

    float s = x, s2 = x * x;
    #pragma unroll
    for (int off = 32; off >= 1; off >>= 1) {
        s  += __shfl_xor(s,  off, 64);
        s2 += __shfl_xor(s2, off, 64);
    }
    float mu  = s * (1.0f / 64.0f);
    float var = s2 * (1.0f / 64.0f) - mu * mu;
    float hval = (x - mu) * rsqrtf(var + 1e-5f) * ln_g[tid] + ln_b[tid];
    h_s[tid] = hval;
    __syncthreads();

    const int j = tid & 31;
    const bool is_s = tid < 32;
    const float* W = is_s ? Ws : We;
    float acc = is_s ? bs[j] : be[j];
    #pragma unroll 8
    for (int m = 0; m < 64; ++m) acc = fmaf(h_s[m], W[j * 64 + m], acc);

    float n2 = acc * acc;
    #pragma unroll
    for (int off = 16; off >= 1; off >>= 1) n2 += __shfl_xor(n2, off, 64);
    float norm = sqrtf(n2);
    float kn = acc / fmaxf(norm, 1e-12f);

    const int base = v * 32 + j;
    if (is_s) { ws[base]        = kn; ws[4096 + base] = acc; }
    else      { ws[2048 + base] = kn; ws[6144 + base] = acc; }
}

// ---------------------------------------------------------------------------
// Kernel 2: delta-rule scan, ROW-PARALLEL (no cross-lane ops in the loop).
// One 64-lane wave per batch. Lane l < 32 owns M_s row l; lane l >= 32 owns
// M_e row l-32. Each lane keeps its full 32-float row in VGPRs; the shared
// k vector is broadcast-read from LDS (same address per half-wave),
// double-buffered one step ahead so LDS latency is off the critical path.
// ---------------------------------------------------------------------------
__global__ __launch_bounds__(64) void scan_kernel(
    const int* __restrict__ seq, const float* __restrict__ ws,
    const float* __restrict__ Wrp, const float* __restrict__ brp,
    const float* __restrict__ Wo, const float* __restrict__ bo,
    float* __restrict__ out)
{
    const int b    = blockIdx.x;
    const int lane = threadIdx.x;      // 0..63
    const int row  = lane & 31;
    const bool is_e = lane >= 32;

    __shared__ __align__(16) float tab[8192];   // ks | ke | vs | ve
    __shared__ int   tok_s[SEQLEN];
    __shared__ float r_s[64];
    __shared__ float t1_s[64];

    // stage vocab tables + token sequence
    {
        const float4* src4 = (const float4*)ws;
        float4* dst4 = (float4*)tab;
        #pragma unroll
        for (int i = 0; i < 32; ++i) dst4[lane + i * 64] = src4[lane + i * 64];
        const int4* sq4 = (const int4*)(seq + b * SEQLEN);
        int4* td4 = (int4*)tok_s;
        #pragma unroll
        for (int i = 0; i < 8; ++i) td4[lane + i * 64] = sq4[lane + i * 64];
    }
    __syncthreads();

    const float* kb = tab + (is_e ? 2048 : 0);
    const float* vb = tab + (is_e ? 6144 : 4096);

    float4 M4[8];
    #pragma unroll
    for (int j = 0; j < 8; ++j) M4[j] = make_float4(0.f, 0.f, 0.f, 0.f);

    const float invL = 1.0f / (float)SEQLEN;

    float4 kA[8], kB[8];
    float  vA, vB;

    auto prefetch = [&](float4 (&kd)[8], float& vd, int tok) {
        const float4* kp = (const float4*)(kb + tok * 32);
        #pragma unroll
        for (int j = 0; j < 8; ++j) kd[j] = kp[j];
        vd = vb[tok * 32 + row];
    };

    auto step = [&](const float4 (&kc)[8], float vcur, int t) {
        float2 q0 = {0.f, 0.f}, q1 = {0.f, 0.f}, q2 = {0.f, 0.f}, q3 = {0.f, 0.f};
        #pragma unroll
        for (int j = 0; j < 8; j += 2) {
            q0.x = fmaf(M4[j].x,   kc[j].x,   q0.x); q0.y = fmaf(M4[j].y,   kc[j].y,   q0.y);
            q1.x = fmaf(M4[j].z,   kc[j].z,   q1.x); q1.y = fmaf(M4[j].w,   kc[j].w,   q1.y);
            q2.x = fmaf(M4[j+1].x, kc[j+1].x, q2.x); q2.y = fmaf(M4[j+1].y, kc[j+1].y, q2.y);
            q3.x = fmaf(M4[j+1].z, kc[j+1].z, q3.x); q3.y = fmaf(M4[j+1].w, kc[j+1].w, q3.y);
        }
        float dot = ((q0.x + q0.y) + (q1.x + q1.y)) + ((q2.x + q2.y) + (q3.x + q3.y));
        float fac = is_e ? (float)(t + 1) * invL : 1.0f;
        float delta = (vcur - dot) * fac;
        #pragma unroll
        for (int j = 0; j < 8; ++j) {
            M4[j].x = fmaf(delta, kc[j].x, M4[j].x);
            M4[j].y = fmaf(delta, kc[j].y, M4[j].y);
            M4[j].z = fmaf(delta, kc[j].z, M4[j].z);
            M4[j].w = fmaf(delta, kc[j].w, M4[j].w);
        }
    };

    // prologue: kA/vA = token[0]
    prefetch(kA, vA, tok_s[0]);
    int tnext = tok_s[1];

    // steps 0..2045 in ping-pong pairs; prefetch is issued before the
    // dependent compute so its LDS latency hides under the 64-FMA step.
    for (int t = 0; t < SEQLEN - 2; t += 2) {
        prefetch(kB, vB, tnext);
        tnext = tok_s[t + 2];
        step(kA, vA, t);

        prefetch(kA, vA, tnext);
        tnext = tok_s[t + 3];
        step(kB, vB, t + 1);
    }
    // final step 2046; prefetch the query key (token[2047]) into kB
    prefetch(kB, vB, tnext);
    step(kA, vA, SEQLEN - 2);

    // readout: r[lane] = M[row,:] . q
    {
        float2 q0 = {0.f, 0.f}, q1 = {0.f, 0.f}, q2 = {0.f, 0.f}, q3 = {0.f, 0.f};
        #pragma unroll
        for (int j = 0; j < 8; j += 2) {
            q0.x = fmaf(M4[j].x,   kB[j].x,   q0.x); q0.y = fmaf(M4[j].y,   kB[j].y,   q0.y);
            q1.x = fmaf(M4[j].z,   kB[j].z,   q1.x); q1.y = fmaf(M4[j].w,   kB[j].w,   q1.y);
            q2.x = fmaf(M4[j+1].x, kB[j+1].x, q2.x); q2.y = fmaf(M4[j+1].y, kB[j+1].y, q2.y);
            q3.x = fmaf(M4[j+1].z, kB[j+1].z, q3.x); q3.y = fmaf(M4[j+1].w, kB[j+1].w, q3.y);
        }
        r_s[lane] = ((q0.x + q0.y) + (q1.x + q1.y)) + ((q2.x + q2.y) + (q3.x + q3.y));
    }
    __syncthreads();

    // out = (r @ Wrp.T + brp) @ Wo.T + bo
    {
        float acc = brp[lane];
        #pragma unroll 8
        for (int m = 0; m < 64; ++m) acc = fmaf(Wrp[lane * 64 + m], r_s[m], acc);
        t1_s[lane] = acc;
    }
    __syncthreads();
    {
        float acc = bo[lane];
        #pragma unroll 8
        for (int m = 0; m < 64; ++m) acc = fmaf(Wo[lane * 64 + m], t1_s[m], acc);
        out[b * 64 + lane] = acc;
    }
}

extern "C" void kernel_launch(void* const* d_in, const int* in_sizes, int n_in,
                              void* d_out, int out_size, void* d_ws, size_t ws_size,
                              hipStream_t stream)
{
    const int*   seq   = (const int*)  d_in[0];
    const float* embed = (const float*)d_in[1];
    const float* W1    = (const float*)d_in[2];
    const float* b1    = (const float*)d_in[3];
    const float* W2    = (const float*)d_in[4];
    const float* b2    = (const float*)d_in[5];
    const float* ln_g  = (const float*)d_in[6];
    const float* ln_b  = (const float*)d_in[7];
    const float* Ws    = (const float*)d_in[8];
    const float* bs    = (const float*)d_in[9];
    const float* We    = (const float*)d_in[10];
    const float* be    = (const float*)d_in[11];
    const float* Wrp   = (const float*)d_in[12];
    const float* brp   = (const float*)d_in[13];
    const float* Wo    = (const float*)d_in[14];
    const float* bo    = (const float*)d_in[15];
    float* ws  = (float*)d_ws;
    float* out = (float*)d_out;

    hipLaunchKernelGGL(vocab_kernel, dim3(VOCAB), dim3(64), 0, stream,
                       embed, W1, b1, W2, b2, ln_g, ln_b, Ws, bs, We, be, ws);
    hipLaunchKernelGGL(scan_kernel, dim3(BATCH), dim3(64), 0, stream,
                       seq, ws, Wrp, brp, Wo, bo, out);
}